// Round 1
// baseline (213.423 us; speedup 1.0000x reference)
//
#include <hip/hip_runtime.h>

// Problem constants (fixed by setup_inputs)
static constexpr int B      = 16;
static constexpr int L      = 8192;
static constexpr int C      = 256;
static constexpr int C4     = C / 4;          // 64 float4 per row
static constexpr int LOUT   = L / 2;          // 4096 output rows per batch
static constexpr int RPT    = 8;              // output rows per thread
static constexpr int CHUNKS = LOUT / RPT;     // 512 chunks per batch
static constexpr int NLOAD  = 2 * RPT + 3;    // 19 input rows touched per chunk

typedef float __attribute__((ext_vector_type(4))) f32x4;

__device__ __forceinline__ float4 f4max(float4 a, float4 b) {
    return make_float4(fmaxf(a.x, b.x), fmaxf(a.y, b.y),
                       fmaxf(a.z, b.z), fmaxf(a.w, b.w));
}

// z[j] = w0*m[2j-1] + w1*m[2j] + w2*m[2j+1] + w3*m[2j+2]
//   m[l] = max(x[l], x[l+1]) for l < L-1; m[L-1] = x[L-1]; m[-1] = m[L] = 0
// Each thread computes RPT=8 consecutive output rows for one float4 column:
// 19 independent row-loads (halo amortized 19/16 = 1.19x vs 7/4 = 1.75x),
// 18 maxes, 8 blended outputs via non-temporal dwordx4 stores.
// Edge semantics: clamped row indices + zeroed edge weights (branch-free).
__global__ __launch_bounds__(256) void maxblurpool_kernel(
    const float4* __restrict__ x,
    const float*  __restrict__ blur,
    const float*  __restrict__ avg,
    float4*       __restrict__ out)
{
    const int t  = blockIdx.x * 256 + threadIdx.x;
    const int c4 = t & (C4 - 1);              // lane -> float4 column (coalesced)
    const int ch = t >> 6;                    // wave-uniform chunk index
    const int b  = ch >> 9;                   // ch / CHUNKS   (CHUNKS == 512)
    const int cj = ch & (CHUNKS - 1);
    const int j0 = cj * RPT;                  // first output row of chunk
    const int i0 = 2 * j0 - 1;                // first input row (may be -1)

    // Coefficients (uniform)
    const float b0 = blur[0], b1 = blur[1], b2 = blur[2];
    const float a0 = avg[0],  a1 = avg[1];
    const float w0 = a0 * b0;
    const float w1 = a0 * b1 + a1 * b0;
    const float w2 = a0 * b2 + a1 * b1;
    const float w3 = a1 * b2;
    const float w0f = (j0 == 0)           ? 0.f : w0;   // m[-1] = 0 (j == 0 only)
    const float w3l = (j0 + RPT == LOUT)  ? 0.f : w3;   // m[L]  = 0 (j == LOUT-1 only)

    const float4* xp = x   + (long)b * L    * C4 + c4;
    float4*       op = out + ((long)b * LOUT + j0) * C4 + c4;

    // 19 independent row loads, all issued before any use. Rows are
    // wave-uniform -> scalar address math. Clamps only fire in the first
    // and last chunk of each batch; clamped duplicates are killed by
    // w0f / w3l below.
    float4 r[NLOAD];
#pragma unroll
    for (int k = 0; k < NLOAD; ++k) {
        int row = i0 + k;
        row = (row < 0) ? 0 : ((row > L - 1) ? L - 1 : row);
        r[k] = xp[(long)row * C4];
    }

    // m[k] == m_global[i0 + k]
    float4 m[NLOAD - 1];
#pragma unroll
    for (int k = 0; k < NLOAD - 1; ++k) m[k] = f4max(r[k], r[k + 1]);

    // z[j0+tt] uses m[2tt] .. m[2tt+3]  (m[2j-1] has local index 2*(j-j0))
#pragma unroll
    for (int tt = 0; tt < RPT; ++tt) {
        const float W0 = (tt == 0)       ? w0f : w0;
        const float W3 = (tt == RPT - 1) ? w3l : w3;
        const float4 ma = m[2 * tt],     mb = m[2 * tt + 1];
        const float4 mc = m[2 * tt + 2], md = m[2 * tt + 3];
        float4 z;
        z.x = W0 * ma.x + w1 * mb.x + w2 * mc.x + W3 * md.x;
        z.y = W0 * ma.y + w1 * mb.y + w2 * mc.y + W3 * md.y;
        z.z = W0 * ma.z + w1 * mb.z + w2 * mc.z + W3 * md.z;
        z.w = W0 * ma.w + w1 * mb.w + w2 * mc.w + W3 * md.w;
        // Output is write-once / never re-read: non-temporal store keeps it
        // from evicting x's halo lines in L2/L3.
        __builtin_nontemporal_store(*(const f32x4*)&z,
                                    (f32x4*)&op[(long)tt * C4]);
    }
}

extern "C" void kernel_launch(void* const* d_in, const int* in_sizes, int n_in,
                              void* d_out, int out_size, void* d_ws, size_t ws_size,
                              hipStream_t stream) {
    const float4* x    = (const float4*)d_in[0];
    const float*  blur = (const float*)d_in[1];
    const float*  avg  = (const float*)d_in[2];
    float4*       out  = (float4*)d_out;

    const int total_threads = B * CHUNKS * C4;   // 524,288
    const int block = 256;
    const int grid  = total_threads / block;     // 2048 blocks
    maxblurpool_kernel<<<grid, block, 0, stream>>>(x, blur, avg, out);
}